// Round 7
// baseline (76.055 us; speedup 1.0000x reference)
//
#include <hip/hip_runtime.h>

#define BINS  256
#define NCOPY 8
#define BLOCK 256
#define GRID  2048

// ---- rare fallback paths (exact semantics, global atomics) ----
__device__ __forceinline__ void gbin1(float x, unsigned int* g) {
    if (x >= 0.0f && x <= 1.0f) {
        unsigned int bin = (unsigned int)(x * 256.0f);   // trunc==floor for x>=0
        bin = bin > 255u ? 255u : bin;
        atomicAdd(&g[bin], 1u);
    }
}
__device__ __forceinline__ void gbin4(float4 v, unsigned int* g) {
    gbin1(v.x, g); gbin1(v.y, g); gbin1(v.z, g); gbin1(v.w, g);
}

// ---- pipe 1: LDS-atomic binning (DS pipe, fire-and-forget) ----
__device__ __forceinline__ void dbin(float x, unsigned int* hc) {
    if (x >= 0.0f && x <= 1.0f) {
        unsigned int bin = (unsigned int)(x * 256.0f);
        bin = bin > 255u ? 255u : bin;
        atomicAdd(&hc[bin * NCOPY], 1u);
    }
}

// ---- pipe 2: ballot bit-slice counting (VALU pipe, zero DS) ----
__device__ __forceinline__ void bs_round(float x, const unsigned long long e[6],
                                         unsigned int cnt[4])
{
    unsigned int bin = (unsigned int)(x * 256.0f);
    bin = bin > 255u ? 255u : bin;

    const unsigned long long mv = __ballot(x >= 0.0f) & __ballot(x <= 1.0f);
    const unsigned long long m0 = __ballot(bin & 1u);
    const unsigned long long m1 = __ballot(bin & 2u);
    const unsigned long long m2 = __ballot(bin & 4u);
    const unsigned long long m3 = __ballot(bin & 8u);
    const unsigned long long m4 = __ballot(bin & 16u);
    const unsigned long long m5 = __ballot(bin & 32u);
    const unsigned long long m6 = __ballot(bin & 64u);
    const unsigned long long m7 = __ballot(bin & 128u);

    const unsigned long long acc = mv
        & (m2 ^ e[0]) & (m3 ^ e[1]) & (m4 ^ e[2])
        & (m5 ^ e[3]) & (m6 ^ e[4]) & (m7 ^ e[5]);

    const unsigned long long nm0 = ~m0, nm1 = ~m1;   // wave-uniform: SALU
    cnt[0] += __popcll(acc & (nm0 & nm1));
    cnt[1] += __popcll(acc & (m0  & nm1));
    cnt[2] += __popcll(acc & (nm0 & m1));
    cnt[3] += __popcll(acc & (m0  & m1));
}

__device__ __forceinline__ void bs4(float4 v, const unsigned long long e[6],
                                    unsigned int cnt[4])
{
    bs_round(v.x, e, cnt);
    bs_round(v.y, e, cnt);
    bs_round(v.z, e, cnt);
    bs_round(v.w, e, cnt);
}

// Wave-role specialized: waves 0-1 = ballot (VALU pipe), waves 2-3 = LDS-atomic
// (DS pipe). Homogeneous per-wave instruction streams so the CU scheduler can
// co-issue the two pipes from different waves (m114-style overlap).
__global__ __launch_bounds__(BLOCK, 8) void hist_kernel(
    const float* __restrict__ img1, const float* __restrict__ img2,
    unsigned int* __restrict__ g_h1, unsigned int* __restrict__ g_h2,
    long long n)
{
    __shared__ unsigned int lh[2][BINS][NCOPY];      // 16 KB, bank-spread copies

    const int tid  = threadIdx.x;
    const int lane = tid & 63;
    const int wid  = tid >> 6;
    const int copy = tid & (NCOPY - 1);

    for (int k = tid; k < 2 * BINS * NCOPY; k += BLOCK)
        ((unsigned int*)lh)[k] = 0u;
    __syncthreads();

    unsigned int c1[4] = {0u, 0u, 0u, 0u};
    unsigned int c2[4] = {0u, 0u, 0u, 0u};
    unsigned int* h1c = &lh[0][0][copy];
    unsigned int* h2c = &lh[1][0][copy];

    const long long n4 = n >> 2;
    const long long stride = (long long)gridDim.x * BLOCK;
    const float4* p1 = (const float4*)img1;
    const float4* p2 = (const float4*)img2;

    const long long i0 = (long long)blockIdx.x * BLOCK + tid;
    const long long trips = n4 / stride;             // uniform across the grid

    if (wid < 2) {
        // ---- ballot role: pure VALU ----
        unsigned long long e[6];
#pragma unroll
        for (int k = 0; k < 6; ++k)
            e[k] = ((lane >> k) & 1) ? 0ull : ~0ull;

        if (trips >= 2) {
            long long i = i0;
            float4 a0 = p1[i],  b0 = p2[i];
            long long ii = i + stride;
            float4 a1 = p1[ii], b1 = p2[ii];
            for (long long t = 0; t + 2 < trips; ++t) {
                const long long in = ii + stride;
                float4 a2 = p1[in], b2 = p2[in];
                bs4(a0, e, c1); bs4(b0, e, c2);
                a0 = a1; b0 = b1; a1 = a2; b1 = b2; ii = in;
            }
            bs4(a0, e, c1); bs4(b0, e, c2);
            bs4(a1, e, c1); bs4(b1, e, c2);
        } else if (trips == 1) {
            float4 a0 = p1[i0], b0 = p2[i0];
            bs4(a0, e, c1); bs4(b0, e, c2);
        }
    } else {
        // ---- DS role: fire-and-forget LDS atomics, near-zero VALU ----
        if (trips >= 2) {
            long long i = i0;
            float4 a0 = p1[i],  b0 = p2[i];
            long long ii = i + stride;
            float4 a1 = p1[ii], b1 = p2[ii];
            for (long long t = 0; t + 2 < trips; ++t) {
                const long long in = ii + stride;
                float4 a2 = p1[in], b2 = p2[in];
                dbin(a0.x, h1c); dbin(a0.y, h1c); dbin(a0.z, h1c); dbin(a0.w, h1c);
                dbin(b0.x, h2c); dbin(b0.y, h2c); dbin(b0.z, h2c); dbin(b0.w, h2c);
                a0 = a1; b0 = b1; a1 = a2; b1 = b2; ii = in;
            }
            dbin(a0.x, h1c); dbin(a0.y, h1c); dbin(a0.z, h1c); dbin(a0.w, h1c);
            dbin(b0.x, h2c); dbin(b0.y, h2c); dbin(b0.z, h2c); dbin(b0.w, h2c);
            dbin(a1.x, h1c); dbin(a1.y, h1c); dbin(a1.z, h1c); dbin(a1.w, h1c);
            dbin(b1.x, h2c); dbin(b1.y, h2c); dbin(b1.z, h2c); dbin(b1.w, h2c);
        } else if (trips == 1) {
            float4 a0 = p1[i0], b0 = p2[i0];
            dbin(a0.x, h1c); dbin(a0.y, h1c); dbin(a0.z, h1c); dbin(a0.w, h1c);
            dbin(b0.x, h2c); dbin(b0.y, h2c); dbin(b0.z, h2c); dbin(b0.w, h2c);
        }
    }

    // leftover float4s (threads past the uniform trip count; empty for this shape)
    {
        const long long i = i0 + trips * stride;
        if (i < n4) {
            gbin4(p1[i], g_h1);
            gbin4(p2[i], g_h2);
        }
    }
    // scalar tail (n % 4; empty for this shape)
    for (long long k = (n4 << 2) + i0; k < n; k += stride) {
        gbin1(img1[k], g_h1);
        gbin1(img2[k], g_h2);
    }

    // ---- flush: merge ballot counters into LDS copies, reduce, global ----
    __syncthreads();   // all DS-role atomics done
#pragma unroll
    for (int j = 0; j < 4; ++j) {
        if (c1[j]) atomicAdd(&lh[0][4 * lane + j][copy], c1[j]);
        if (c2[j]) atomicAdd(&lh[1][4 * lane + j][copy], c2[j]);
    }
    __syncthreads();

    for (int b = tid; b < BINS; b += BLOCK) {
        unsigned int s1 = 0u, s2 = 0u;
#pragma unroll
        for (int c = 0; c < NCOPY; ++c) { s1 += lh[0][b][c]; s2 += lh[1][b][c]; }
        if (s1) atomicAdd(&g_h1[b], s1);
        if (s2) atomicAdd(&g_h2[b], s2);
    }
}

// Pass 2: loss = sum_i |c1[i]/N1 - c2[i]/N2| / 256, double precision.
__global__ __launch_bounds__(BINS) void finalize_kernel(
    const unsigned int* __restrict__ h1, const unsigned int* __restrict__ h2,
    float* __restrict__ out)
{
    const int tid = threadIdx.x;          // one thread per bin
    const unsigned int c1 = h1[tid];
    const unsigned int c2 = h2[tid];

    __shared__ unsigned int s1[4], s2[4];
    __shared__ double sd[4];

    unsigned int r1 = c1, r2 = c2;
#pragma unroll
    for (int off = 32; off > 0; off >>= 1) {
        r1 += __shfl_down(r1, off);
        r2 += __shfl_down(r2, off);
    }
    if ((tid & 63) == 0) { s1[tid >> 6] = r1; s2[tid >> 6] = r2; }
    __syncthreads();

    const double N1 = (double)(s1[0] + s1[1] + s1[2] + s1[3]);
    const double N2 = (double)(s2[0] + s2[1] + s2[2] + s2[3]);

    double d = fabs((double)c1 / N1 - (double)c2 / N2);
#pragma unroll
    for (int off = 32; off > 0; off >>= 1)
        d += __shfl_down(d, off);
    if ((tid & 63) == 0) sd[tid >> 6] = d;
    __syncthreads();

    if (tid == 0) {
        double tot = sd[0] + sd[1] + sd[2] + sd[3];
        out[0] = (float)(tot / (double)BINS);
    }
}

extern "C" void kernel_launch(void* const* d_in, const int* in_sizes, int n_in,
                              void* d_out, int out_size, void* d_ws, size_t ws_size,
                              hipStream_t stream) {
    const float* img1 = (const float*)d_in[0];
    const float* img2 = (const float*)d_in[1];
    const long long n = (long long)in_sizes[0];

    unsigned int* g_h1 = (unsigned int*)d_ws;
    unsigned int* g_h2 = g_h1 + BINS;

    hipMemsetAsync(d_ws, 0, 2 * BINS * sizeof(unsigned int), stream);

    const long long n4 = n >> 2;
    int blocks = (int)((n4 + BLOCK - 1) / BLOCK);
    if (blocks > GRID) blocks = GRID;
    if (blocks < 1) blocks = 1;

    hist_kernel<<<blocks, BLOCK, 0, stream>>>(img1, img2, g_h1, g_h2, n);
    finalize_kernel<<<1, BINS, 0, stream>>>(g_h1, g_h2, (float*)d_out);
}

// Round 8
// 66.503 us; speedup vs baseline: 1.1436x; 1.1436x over previous
//
#include <hip/hip_runtime.h>

#define BINS  256
#define NCOPY 8
#define BLOCK 512      // 8 waves: wid 0-3 ballot (one per SIMD), wid 4-7 DS (one per SIMD)
#define HALFT 256      // threads per role per block
#define GRID  768      // 3 blocks/CU exactly (24 waves/CU), 16 trips/role for this shape

typedef unsigned int u32;
typedef unsigned long long u64;

// ---- rare fallback paths (exact semantics, global atomics) ----
__device__ __forceinline__ void gbin1(float x, u32* g) {
    if (x >= 0.0f && x <= 1.0f) {
        u32 bin = (u32)(x * 256.0f);     // trunc==floor for x>=0; matches JAX
        bin = bin > 255u ? 255u : bin;
        atomicAdd(&g[bin], 1u);
    }
}
__device__ __forceinline__ void gbin4(float4 v, u32* g) {
    gbin1(v.x, g); gbin1(v.y, g); gbin1(v.z, g); gbin1(v.w, g);
}

// ---- DS role: fire-and-forget LDS atomic ----
__device__ __forceinline__ void dbin(float x, u32* hc) {
    if (x >= 0.0f && x <= 1.0f) {
        u32 bin = (u32)(x * 256.0f);
        bin = bin > 255u ? 255u : bin;
        atomicAdd(&hc[bin * NCOPY], 1u);
    }
}

// ---- ballot role: bit-slice count, 32-bit halves, masks stay SGPR ----
// Lane owns bins 4*lane..4*lane+3 (bin bits 7:2 == lane bits 5:0, bits 1:0 = j).
__device__ __forceinline__ void bs_round(float x, const u32 e[6], u32 cnt[4])
{
    u32 bin = (u32)(x * 256.0f);
    bin = bin > 255u ? 255u : bin;

    const u64 mv = __ballot(x >= 0.0f) & __ballot(x <= 1.0f);
    const u64 b0 = __ballot((bin & 1u) != 0u);
    const u64 b1 = __ballot((bin & 2u) != 0u);
    const u64 b2 = __ballot((bin & 4u) != 0u);
    const u64 b3 = __ballot((bin & 8u) != 0u);
    const u64 b4 = __ballot((bin & 16u) != 0u);
    const u64 b5 = __ballot((bin & 32u) != 0u);
    const u64 b6 = __ballot((bin & 64u) != 0u);
    const u64 b7 = __ballot((bin & 128u) != 0u);

    // per-lane fold in 32-bit halves: e[k] == (lane bit k) ? 0 : ~0
    u32 aLo = (u32)mv
            & (((u32)b2) ^ e[0]) & (((u32)b3) ^ e[1]) & (((u32)b4) ^ e[2])
            & (((u32)b5) ^ e[3]) & (((u32)b6) ^ e[4]) & (((u32)b7) ^ e[5]);
    u32 aHi = (u32)(mv >> 32)
            & (((u32)(b2 >> 32)) ^ e[0]) & (((u32)(b3 >> 32)) ^ e[1])
            & (((u32)(b4 >> 32)) ^ e[2]) & (((u32)(b5 >> 32)) ^ e[3])
            & (((u32)(b6 >> 32)) ^ e[4]) & (((u32)(b7 >> 32)) ^ e[5]);

    // wave-uniform combos (SALU), then per-lane and+popcnt
    const u32 p0l = (u32)b0, p0h = (u32)(b0 >> 32);
    const u32 p1l = (u32)b1, p1h = (u32)(b1 >> 32);
    cnt[0] += __popc(aLo & ~(p0l | p1l)) + __popc(aHi & ~(p0h | p1h));
    cnt[1] += __popc(aLo & (p0l & ~p1l)) + __popc(aHi & (p0h & ~p1h));
    cnt[2] += __popc(aLo & (~p0l & p1l)) + __popc(aHi & (~p0h & p1h));
    cnt[3] += __popc(aLo & (p0l & p1l))  + __popc(aHi & (p0h & p1h));
}

__device__ __forceinline__ void bs4(float4 v, const u32 e[6], u32 cnt[4])
{
    bs_round(v.x, e, cnt);
    bs_round(v.y, e, cnt);
    bs_round(v.z, e, cnt);
    bs_round(v.w, e, cnt);
}

__global__ __launch_bounds__(BLOCK, 6) void hist_kernel(
    const float* __restrict__ img1, const float* __restrict__ img2,
    u32* __restrict__ g_h1, u32* __restrict__ g_h2,
    long long n)
{
    __shared__ u32 lh[2][BINS][NCOPY];       // 16 KB, bank-spread copies

    const int tid  = threadIdx.x;
    const int lane = tid & 63;
    const int copy = tid & (NCOPY - 1);

    for (int k = tid; k < 2 * BINS * NCOPY; k += BLOCK)
        ((u32*)lh)[k] = 0u;
    __syncthreads();

    u32 cnt1[4] = {0u, 0u, 0u, 0u};
    u32 cnt2[4] = {0u, 0u, 0u, 0u};
    u32* h1c = &lh[0][0][copy];
    u32* h2c = &lh[1][0][copy];

    const long long n4 = n >> 2;
    const long long S  = (long long)gridDim.x * HALFT;     // quads per role per trip
    const long long QB = ((n4 / 2) / S) * S;               // ballot value share (f=0.5)
    const long long tripsB = QB / S;
    const long long tripsD = (n4 - QB) / S;
    const long long uniform_end = QB + tripsD * S;

    const float4* p1 = (const float4*)img1;
    const float4* p2 = (const float4*)img2;

    if (tid < HALFT) {
        // ---- ballot role (waves 0-3, one per SIMD): pure VALU ----
        u32 e[6];
#pragma unroll
        for (int k = 0; k < 6; ++k)
            e[k] = ((lane >> k) & 1) ? 0u : 0xFFFFFFFFu;

        long long i = (long long)blockIdx.x * HALFT + tid;       // quads [0, QB)
        if (tripsB >= 2) {
            float4 a0 = p1[i],  b0 = p2[i];
            long long ii = i + S;
            float4 a1 = p1[ii], b1 = p2[ii];
            for (long long t = 0; t + 2 < tripsB; ++t) {
                const long long in = ii + S;
                float4 a2 = p1[in], b2v = p2[in];
                bs4(a0, e, cnt1); bs4(b0, e, cnt2);
                a0 = a1; b0 = b1; a1 = a2; b1 = b2v; ii = in;
            }
            bs4(a0, e, cnt1); bs4(b0, e, cnt2);
            bs4(a1, e, cnt1); bs4(b1, e, cnt2);
        } else if (tripsB == 1) {
            float4 a0 = p1[i], b0 = p2[i];
            bs4(a0, e, cnt1); bs4(b0, e, cnt2);
        }
    } else {
        // ---- DS role (waves 4-7, one per SIMD): fire-and-forget LDS atomics ----
        long long i = QB + (long long)blockIdx.x * HALFT + (tid - HALFT);  // quads [QB, n4)
        if (tripsD >= 2) {
            float4 a0 = p1[i],  b0 = p2[i];
            long long ii = i + S;
            float4 a1 = p1[ii], b1 = p2[ii];
            for (long long t = 0; t + 2 < tripsD; ++t) {
                const long long in = ii + S;
                float4 a2 = p1[in], b2v = p2[in];
                dbin(a0.x, h1c); dbin(a0.y, h1c); dbin(a0.z, h1c); dbin(a0.w, h1c);
                dbin(b0.x, h2c); dbin(b0.y, h2c); dbin(b0.z, h2c); dbin(b0.w, h2c);
                a0 = a1; b0 = b1; a1 = a2; b1 = b2v; ii = in;
            }
            dbin(a0.x, h1c); dbin(a0.y, h1c); dbin(a0.z, h1c); dbin(a0.w, h1c);
            dbin(b0.x, h2c); dbin(b0.y, h2c); dbin(b0.z, h2c); dbin(b0.w, h2c);
            dbin(a1.x, h1c); dbin(a1.y, h1c); dbin(a1.z, h1c); dbin(a1.w, h1c);
            dbin(b1.x, h2c); dbin(b1.y, h2c); dbin(b1.z, h2c); dbin(b1.w, h2c);
        } else if (tripsD == 1) {
            float4 a0 = p1[i], b0 = p2[i];
            dbin(a0.x, h1c); dbin(a0.y, h1c); dbin(a0.z, h1c); dbin(a0.w, h1c);
            dbin(b0.x, h2c); dbin(b0.y, h2c); dbin(b0.z, h2c); dbin(b0.w, h2c);
        }
    }

    // generic tails (empty for this shape)
    {
        const long long gtid = (long long)blockIdx.x * BLOCK + tid;
        const long long nthr = (long long)gridDim.x * BLOCK;
        for (long long q = uniform_end + gtid; q < n4; q += nthr) {
            gbin4(p1[q], g_h1);
            gbin4(p2[q], g_h2);
        }
        for (long long k2 = (n4 << 2) + gtid; k2 < n; k2 += nthr) {
            gbin1(img1[k2], g_h1);
            gbin1(img2[k2], g_h2);
        }
    }

    // ---- flush: merge ballot counters into LDS copies, reduce, global ----
    __syncthreads();                     // all DS-role atomics done
#pragma unroll
    for (int j = 0; j < 4; ++j) {        // DS threads have cnt==0, skip
        if (cnt1[j]) atomicAdd(&lh[0][4 * lane + j][copy], cnt1[j]);
        if (cnt2[j]) atomicAdd(&lh[1][4 * lane + j][copy], cnt2[j]);
    }
    __syncthreads();

    for (int b = tid; b < BINS; b += BLOCK) {
        u32 s1 = 0u, s2 = 0u;
#pragma unroll
        for (int c = 0; c < NCOPY; ++c) { s1 += lh[0][b][c]; s2 += lh[1][b][c]; }
        if (s1) atomicAdd(&g_h1[b], s1);
        if (s2) atomicAdd(&g_h2[b], s2);
    }
}

// Pass 2: loss = sum_i |c1[i]/N1 - c2[i]/N2| / 256, double precision.
__global__ __launch_bounds__(BINS) void finalize_kernel(
    const u32* __restrict__ h1, const u32* __restrict__ h2,
    float* __restrict__ out)
{
    const int tid = threadIdx.x;          // one thread per bin
    const u32 c1 = h1[tid];
    const u32 c2 = h2[tid];

    __shared__ u32 s1[4], s2[4];
    __shared__ double sd[4];

    u32 r1 = c1, r2 = c2;
#pragma unroll
    for (int off = 32; off > 0; off >>= 1) {
        r1 += __shfl_down(r1, off);
        r2 += __shfl_down(r2, off);
    }
    if ((tid & 63) == 0) { s1[tid >> 6] = r1; s2[tid >> 6] = r2; }
    __syncthreads();

    const double N1 = (double)(s1[0] + s1[1] + s1[2] + s1[3]);
    const double N2 = (double)(s2[0] + s2[1] + s2[2] + s2[3]);

    double d = fabs((double)c1 / N1 - (double)c2 / N2);
#pragma unroll
    for (int off = 32; off > 0; off >>= 1)
        d += __shfl_down(d, off);
    if ((tid & 63) == 0) sd[tid >> 6] = d;
    __syncthreads();

    if (tid == 0) {
        double tot = sd[0] + sd[1] + sd[2] + sd[3];
        out[0] = (float)(tot / (double)BINS);
    }
}

extern "C" void kernel_launch(void* const* d_in, const int* in_sizes, int n_in,
                              void* d_out, int out_size, void* d_ws, size_t ws_size,
                              hipStream_t stream) {
    const float* img1 = (const float*)d_in[0];
    const float* img2 = (const float*)d_in[1];
    const long long n = (long long)in_sizes[0];

    u32* g_h1 = (u32*)d_ws;
    u32* g_h2 = g_h1 + BINS;

    hipMemsetAsync(d_ws, 0, 2 * BINS * sizeof(u32), stream);

    hist_kernel<<<GRID, BLOCK, 0, stream>>>(img1, img2, g_h1, g_h2, n);
    finalize_kernel<<<1, BINS, 0, stream>>>(g_h1, g_h2, (float*)d_out);
}

// Round 9
// 52.426 us; speedup vs baseline: 1.4507x; 1.2685x over previous
//
#include <hip/hip_runtime.h>

#define BINS  256
#define NCOPY 8
#define BLOCK 512      // 8 waves: wid 0-3 ballot (one per SIMD), wid 4-7 DS (one per SIMD)
#define HALFT 256      // threads per role per block
#define GRID  1024     // 4 blocks/CU exactly (32 waves/CU); 24 trips total for this shape

typedef unsigned int u32;
typedef unsigned long long u64;

// ---- rare fallback paths (exact semantics, global atomics) ----
__device__ __forceinline__ void gbin1(float x, u32* g) {
    if (x >= 0.0f && x <= 1.0f) {
        u32 bin = (u32)(x * 256.0f);     // trunc==floor for x>=0; matches JAX
        bin = bin > 255u ? 255u : bin;
        atomicAdd(&g[bin], 1u);
    }
}
__device__ __forceinline__ void gbin4(float4 v, u32* g) {
    gbin1(v.x, g); gbin1(v.y, g); gbin1(v.z, g); gbin1(v.w, g);
}

// ---- DS role: fire-and-forget LDS atomic (measured ~1 lane-op/cyc/CU) ----
__device__ __forceinline__ void dbin(float x, u32* hc) {
    if (x >= 0.0f && x <= 1.0f) {
        u32 bin = (u32)(x * 256.0f);
        bin = bin > 255u ? 255u : bin;
        atomicAdd(&hc[bin * NCOPY], 1u);
    }
}

// ---- ballot role: bit-slice count (VALU pipe, zero DS) ----
// Lane owns bins 4*lane..4*lane+3 (bin bits 7:2 vs lane bits 5:0; bits 1:0 = j).
__device__ __forceinline__ void bs_round(float x, const u32 e[6], u32 cnt[4])
{
    u32 bin = (u32)(x * 256.0f);
    bin = bin > 255u ? 255u : bin;

    const u64 mv = __ballot(x >= 0.0f) & __ballot(x <= 1.0f);
    const u64 b0 = __ballot((bin & 1u) != 0u);
    const u64 b1 = __ballot((bin & 2u) != 0u);
    const u64 b2 = __ballot((bin & 4u) != 0u);
    const u64 b3 = __ballot((bin & 8u) != 0u);
    const u64 b4 = __ballot((bin & 16u) != 0u);
    const u64 b5 = __ballot((bin & 32u) != 0u);
    const u64 b6 = __ballot((bin & 64u) != 0u);
    const u64 b7 = __ballot((bin & 128u) != 0u);

    // per-lane fold in 32-bit halves: e[k] == (lane bit k) ? 0 : ~0
    u32 aLo = (u32)mv
            & (((u32)b2) ^ e[0]) & (((u32)b3) ^ e[1]) & (((u32)b4) ^ e[2])
            & (((u32)b5) ^ e[3]) & (((u32)b6) ^ e[4]) & (((u32)b7) ^ e[5]);
    u32 aHi = (u32)(mv >> 32)
            & (((u32)(b2 >> 32)) ^ e[0]) & (((u32)(b3 >> 32)) ^ e[1])
            & (((u32)(b4 >> 32)) ^ e[2]) & (((u32)(b5 >> 32)) ^ e[3])
            & (((u32)(b6 >> 32)) ^ e[4]) & (((u32)(b7 >> 32)) ^ e[5]);

    // wave-uniform low-bit combos (SALU), then per-lane and + popcount
    const u64 c00 = ~(b0 | b1);
    const u64 c01 = b0 & ~b1;
    const u64 c10 = ~b0 & b1;
    const u64 c11 = b0 & b1;
    cnt[0] += __popc(aLo & (u32)c00) + __popc(aHi & (u32)(c00 >> 32));
    cnt[1] += __popc(aLo & (u32)c01) + __popc(aHi & (u32)(c01 >> 32));
    cnt[2] += __popc(aLo & (u32)c10) + __popc(aHi & (u32)(c10 >> 32));
    cnt[3] += __popc(aLo & (u32)c11) + __popc(aHi & (u32)(c11 >> 32));
}

__device__ __forceinline__ void bs4(float4 v, const u32 e[6], u32 cnt[4])
{
    bs_round(v.x, e, cnt);
    bs_round(v.y, e, cnt);
    bs_round(v.z, e, cnt);
    bs_round(v.w, e, cnt);
}

// Wave-role specialized across all 4 SIMDs: waves 0-3 ballot, waves 4-7 DS.
// Value-range split f = 1/3 ballot : 2/3 DS, balanced to measured pipe rates
// (ballot ~300 G values/s, LDS-scatter ~614 G values/s chip-wide).
__global__ __launch_bounds__(BLOCK, 8) void hist_kernel(
    const float* __restrict__ img1, const float* __restrict__ img2,
    u32* __restrict__ g_h1, u32* __restrict__ g_h2,
    long long n)
{
    __shared__ u32 lh[2][BINS][NCOPY];       // 16 KB, bank-spread copies

    const int tid  = threadIdx.x;
    const int lane = tid & 63;
    const int copy = tid & (NCOPY - 1);

    for (int k = tid; k < 2 * BINS * NCOPY; k += BLOCK)
        ((u32*)lh)[k] = 0u;
    __syncthreads();

    u32 cnt1[4] = {0u, 0u, 0u, 0u};
    u32 cnt2[4] = {0u, 0u, 0u, 0u};
    u32* h1c = &lh[0][0][copy];
    u32* h2c = &lh[1][0][copy];

    const long long n4 = n >> 2;
    const long long S  = (long long)gridDim.x * HALFT;     // quads per role per trip
    const long long tripsTot = n4 / S;
    const long long tripsB = tripsTot / 3;                 // ballot share f = 1/3
    const long long tripsD = tripsTot - tripsB;
    const long long QB = tripsB * S;                       // ballot covers quads [0, QB)
    const long long uniform_end = QB + tripsD * S;         // == n4 when divisible

    const float4* p1 = (const float4*)img1;
    const float4* p2 = (const float4*)img2;

    if (tid < HALFT) {
        // ---- ballot role (one wave per SIMD per block): pure VALU ----
        u32 e[6];
#pragma unroll
        for (int k = 0; k < 6; ++k)
            e[k] = ((lane >> k) & 1) ? 0u : 0xFFFFFFFFu;

        long long i = (long long)blockIdx.x * HALFT + tid;       // quads [0, QB)
        if (tripsB >= 2) {
            float4 a0 = p1[i],  b0 = p2[i];
            long long ii = i + S;
            float4 a1 = p1[ii], b1 = p2[ii];
            for (long long t = 0; t + 2 < tripsB; ++t) {
                const long long in = ii + S;
                float4 a2 = p1[in], b2v = p2[in];
                bs4(a0, e, cnt1); bs4(b0, e, cnt2);
                a0 = a1; b0 = b1; a1 = a2; b1 = b2v; ii = in;
            }
            bs4(a0, e, cnt1); bs4(b0, e, cnt2);
            bs4(a1, e, cnt1); bs4(b1, e, cnt2);
        } else if (tripsB == 1) {
            float4 a0 = p1[i], b0 = p2[i];
            bs4(a0, e, cnt1); bs4(b0, e, cnt2);
        }
    } else {
        // ---- DS role (one wave per SIMD per block): fire-and-forget LDS atomics ----
        long long i = QB + (long long)blockIdx.x * HALFT + (tid - HALFT);  // quads [QB, n4)
        if (tripsD >= 2) {
            float4 a0 = p1[i],  b0 = p2[i];
            long long ii = i + S;
            float4 a1 = p1[ii], b1 = p2[ii];
            for (long long t = 0; t + 2 < tripsD; ++t) {
                const long long in = ii + S;
                float4 a2 = p1[in], b2v = p2[in];
                dbin(a0.x, h1c); dbin(a0.y, h1c); dbin(a0.z, h1c); dbin(a0.w, h1c);
                dbin(b0.x, h2c); dbin(b0.y, h2c); dbin(b0.z, h2c); dbin(b0.w, h2c);
                a0 = a1; b0 = b1; a1 = a2; b1 = b2v; ii = in;
            }
            dbin(a0.x, h1c); dbin(a0.y, h1c); dbin(a0.z, h1c); dbin(a0.w, h1c);
            dbin(b0.x, h2c); dbin(b0.y, h2c); dbin(b0.z, h2c); dbin(b0.w, h2c);
            dbin(a1.x, h1c); dbin(a1.y, h1c); dbin(a1.z, h1c); dbin(a1.w, h1c);
            dbin(b1.x, h2c); dbin(b1.y, h2c); dbin(b1.z, h2c); dbin(b1.w, h2c);
        } else if (tripsD == 1) {
            float4 a0 = p1[i], b0 = p2[i];
            dbin(a0.x, h1c); dbin(a0.y, h1c); dbin(a0.z, h1c); dbin(a0.w, h1c);
            dbin(b0.x, h2c); dbin(b0.y, h2c); dbin(b0.z, h2c); dbin(b0.w, h2c);
        }
    }

    // generic tails (empty for this shape)
    {
        const long long gtid = (long long)blockIdx.x * BLOCK + tid;
        const long long nthr = (long long)gridDim.x * BLOCK;
        for (long long q = uniform_end + gtid; q < n4; q += nthr) {
            gbin4(p1[q], g_h1);
            gbin4(p2[q], g_h2);
        }
        for (long long k2 = (n4 << 2) + gtid; k2 < n; k2 += nthr) {
            gbin1(img1[k2], g_h1);
            gbin1(img2[k2], g_h2);
        }
    }

    // ---- flush: merge ballot counters into LDS copies, reduce, global ----
    __syncthreads();                     // all DS-role atomics done
#pragma unroll
    for (int j = 0; j < 4; ++j) {        // DS threads have cnt==0, skip
        if (cnt1[j]) atomicAdd(&lh[0][4 * lane + j][copy], cnt1[j]);
        if (cnt2[j]) atomicAdd(&lh[1][4 * lane + j][copy], cnt2[j]);
    }
    __syncthreads();

    for (int b = tid; b < BINS; b += BLOCK) {
        u32 s1 = 0u, s2 = 0u;
#pragma unroll
        for (int c = 0; c < NCOPY; ++c) { s1 += lh[0][b][c]; s2 += lh[1][b][c]; }
        if (s1) atomicAdd(&g_h1[b], s1);
        if (s2) atomicAdd(&g_h2[b], s2);
    }
}

// Pass 2: loss = sum_i |c1[i]/N1 - c2[i]/N2| / 256, double precision.
__global__ __launch_bounds__(BINS) void finalize_kernel(
    const u32* __restrict__ h1, const u32* __restrict__ h2,
    float* __restrict__ out)
{
    const int tid = threadIdx.x;          // one thread per bin
    const u32 c1 = h1[tid];
    const u32 c2 = h2[tid];

    __shared__ u32 s1[4], s2[4];
    __shared__ double sd[4];

    u32 r1 = c1, r2 = c2;
#pragma unroll
    for (int off = 32; off > 0; off >>= 1) {
        r1 += __shfl_down(r1, off);
        r2 += __shfl_down(r2, off);
    }
    if ((tid & 63) == 0) { s1[tid >> 6] = r1; s2[tid >> 6] = r2; }
    __syncthreads();

    const double N1 = (double)(s1[0] + s1[1] + s1[2] + s1[3]);
    const double N2 = (double)(s2[0] + s2[1] + s2[2] + s2[3]);

    double d = fabs((double)c1 / N1 - (double)c2 / N2);
#pragma unroll
    for (int off = 32; off > 0; off >>= 1)
        d += __shfl_down(d, off);
    if ((tid & 63) == 0) sd[tid >> 6] = d;
    __syncthreads();

    if (tid == 0) {
        double tot = sd[0] + sd[1] + sd[2] + sd[3];
        out[0] = (float)(tot / (double)BINS);
    }
}

extern "C" void kernel_launch(void* const* d_in, const int* in_sizes, int n_in,
                              void* d_out, int out_size, void* d_ws, size_t ws_size,
                              hipStream_t stream) {
    const float* img1 = (const float*)d_in[0];
    const float* img2 = (const float*)d_in[1];
    const long long n = (long long)in_sizes[0];

    u32* g_h1 = (u32*)d_ws;
    u32* g_h2 = g_h1 + BINS;

    hipMemsetAsync(d_ws, 0, 2 * BINS * sizeof(u32), stream);

    hist_kernel<<<GRID, BLOCK, 0, stream>>>(img1, img2, g_h1, g_h2, n);
    finalize_kernel<<<1, BINS, 0, stream>>>(g_h1, g_h2, (float*)d_out);
}